// Round 1
// baseline (465.617 us; speedup 1.0000x reference)
//
#include <hip/hip_runtime.h>
#include <math.h>

#define PATTERNS 6
#define ITERS 50
#define LAMBDA_ 100.0f
// 1/(sqrt(2)*SIGMA), SIGMA=1.5
#define CST 0.47140452079103173f

// 16 lanes per job (one ROI row per lane), 4 jobs per wave.
// All data register-resident; 3-sum butterfly reduction per iteration.
__global__ __launch_bounds__(256, 4) void intensity_kernel(
    const float* __restrict__ params,
    const float* __restrict__ data,
    float* __restrict__ out,
    int njobs)
{
    const int tid = blockIdx.x * 256 + threadIdx.x;
    const int job = tid >> 4;
    const int row = tid & 15;
    if (job >= njobs) return;
    const int spot = job / PATTERNS;

    const float x = params[spot * 5 + 0];
    const float y = params[spot * 5 + 1];
    float I = params[spot * 5 + 4] * (1.0f / PATTERNS);
    float bg = 0.0f;

    // psf row `row`: Ey(row) * Ex(c), pixel-integrated Gaussian
    const float fy = (float)row - y;
    const float eyl = 0.5f * (erff((fy + 1.0f) * CST) - erff(fy * CST));
    float g[16];
    {
        float ep = erff((0.0f - x) * CST);
        #pragma unroll
        for (int c = 0; c < 16; ++c) {
            float en = erff(((float)(c + 1) - x) * CST);
            g[c] = eyl * (0.5f * (en - ep));
            ep = en;
        }
    }

    // load this lane's 16 samples (one ROI row) into registers
    float smp[16];
    {
        const float4* dp = reinterpret_cast<const float4*>(data + (size_t)job * 256 + row * 16);
        #pragma unroll
        for (int q = 0; q < 4; ++q) {
            float4 v = dp[q];
            smp[4 * q + 0] = v.x;
            smp[4 * q + 1] = v.y;
            smp[4 * q + 2] = v.z;
            smp[4 * q + 3] = v.w;
        }
    }

    // S_psf = sum of psf over all 256 pixels (for folded -1 in df)
    float spsf = 0.0f;
    #pragma unroll
    for (int c = 0; c < 16; ++c) spsf += g[c];
    #pragma unroll
    for (int m = 1; m < 16; m <<= 1) spsf += __shfl_xor(spsf, m, 16);

    for (int it = 0; it < ITERS; ++it) {
        float U0 = 0.0f, U1 = 0.0f, U2 = 0.0f;   // sum u, sum u*g, sum u*g^2
        #pragma unroll
        for (int p = 0; p < 16; ++p) {
            float mu = fmaf(I, g[p], bg);
            mu = fmaxf(mu, 1e-9f);
            float r = __builtin_amdgcn_rcpf(mu);
            float u = smp[p] * r * r;            // smp/mu^2
            float w = u * g[p];
            U0 += u;
            U1 += w;
            U2 = fmaf(w, g[p], U2);
        }
        #pragma unroll
        for (int m = 1; m < 16; m <<= 1) {
            U0 += __shfl_xor(U0, m, 16);
            U1 += __shfl_xor(U1, m, 16);
            U2 += __shfl_xor(U2, m, 16);
        }
        // t = u*mu identity: Σt = I*U1 + bg*U0, Σt*g = I*U2 + bg*U1
        float a00 = U2 + LAMBDA_;
        float a01 = U1;
        float a11 = U0 + LAMBDA_;
        float st  = I * U1 + bg * U0;
        float stp = I * U2 + bg * U1;
        float b0 = stp - spsf;
        float b1 = st - 256.0f;
        float det = a00 * a11 - a01 * a01;
        float rd = __builtin_amdgcn_rcpf(det);
        float dI  = (a11 * b0 - a01 * b1) * rd;
        float dbg = (a00 * b1 - a01 * b0) * rd;
        I  = fminf(fmaxf(I + dI, 1.0f), 1000000.0f);
        bg = fminf(fmaxf(bg + dbg, 1.0f), 1000.0f);
    }

    // epilogue: CRLB + chisq
    float F00 = 0.0f, F01 = 0.0f, F11 = 0.0f, chis = 0.0f;
    #pragma unroll
    for (int p = 0; p < 16; ++p) {
        float mu = fmaf(I, g[p], bg);
        float muc = fmaxf(mu, 1e-9f);
        float inv = __builtin_amdgcn_rcpf(muc);
        F00 = fmaf(g[p] * g[p], inv, F00);
        F01 = fmaf(g[p], inv, F01);
        F11 += inv;
        float d = smp[p] - mu;
        chis = fmaf(d * d, __builtin_amdgcn_rcpf(mu + 0.01f), chis);
    }
    #pragma unroll
    for (int m = 1; m < 16; m <<= 1) {
        F00  += __shfl_xor(F00, m, 16);
        F01  += __shfl_xor(F01, m, 16);
        F11  += __shfl_xor(F11, m, 16);
        chis += __shfl_xor(chis, m, 16);
    }
    if (row == 0) {
        float detF = F00 * F11 - F01 * F01;
        float rdF = __builtin_amdgcn_rcpf(detF);
        float c0 = sqrtf(F11 * rdF);
        float c1 = sqrtf(F00 * rdF);
        float* o = out + (size_t)job * 5;
        o[0] = I;
        o[1] = bg;
        o[2] = c0;
        o[3] = c1;
        o[4] = chis;
    }
}

extern "C" void kernel_launch(void* const* d_in, const int* in_sizes, int n_in,
                              void* d_out, int out_size, void* d_ws, size_t ws_size,
                              hipStream_t stream) {
    const float* params = (const float*)d_in[0];
    const float* data   = (const float*)d_in[1];
    float* out = (float*)d_out;
    int nspots = in_sizes[0] / 5;
    int njobs = nspots * PATTERNS;
    long long nthreads = (long long)njobs * 16;
    int blocks = (int)((nthreads + 255) / 256);
    intensity_kernel<<<dim3(blocks), dim3(256), 0, stream>>>(params, data, out, njobs);
}

// Round 3
// 306.402 us; speedup vs baseline: 1.5196x; 1.5196x over previous
//
#include <hip/hip_runtime.h>
#include <math.h>

#define PATTERNS 6
#define ITERS 50
#define LAMBDA_ 100.0f
// 1/(sqrt(2)*SIGMA), SIGMA=1.5
#define CST 0.47140452079103173f

typedef float v2f __attribute__((ext_vector_type(2)));

// all-lanes sum within 8-lane groups (proven __shfl_xor path)
__device__ __forceinline__ float grpsum8(float x) {
    x += __shfl_xor(x, 1, 8);
    x += __shfl_xor(x, 2, 8);
    x += __shfl_xor(x, 4, 8);
    return x;
}

// 8 lanes per job: lane `sub` owns rows 2*sub and 2*sub+1 (32 px, register-resident).
// Packed-fp32 inner loop, paired rcp, shfl_xor reductions.
__global__ __launch_bounds__(256, 4) void intensity_kernel(
    const float* __restrict__ params,
    const float* __restrict__ data,
    float* __restrict__ out,
    int njobs)
{
    const int tid = blockIdx.x * 256 + threadIdx.x;
    const int job = tid >> 3;
    const int sub = tid & 7;
    if (job >= njobs) return;
    const int spot = job / PATTERNS;

    const float x = params[spot * 5 + 0];
    const float y = params[spot * 5 + 1];
    float I = params[spot * 5 + 4] * (1.0f / PATTERNS);
    float bg = 0.0f;

    // psf for this lane's two rows: Ey(r) * Ex(c)
    const float r0 = (float)(2 * sub);
    const float ey_a = erff((r0 - y) * CST);
    const float ey_b = erff((r0 + 1.0f - y) * CST);
    const float ey_c = erff((r0 + 2.0f - y) * CST);
    const float eyl0 = 0.5f * (ey_b - ey_a);
    const float eyl1 = 0.5f * (ey_c - ey_b);

    // g2[0..7]  = row 2*sub   (pixel pairs), g2[8..15] = row 2*sub+1
    v2f g2[16];
    {
        float ex[16];
        float ep = erff((0.0f - x) * CST);
        #pragma unroll
        for (int c = 0; c < 16; ++c) {
            float en = erff(((float)(c + 1) - x) * CST);
            ex[c] = 0.5f * (en - ep);
            ep = en;
        }
        #pragma unroll
        for (int k = 0; k < 8; ++k) {
            g2[k]     = (v2f){eyl0 * ex[2 * k], eyl0 * ex[2 * k + 1]};
            g2[8 + k] = (v2f){eyl1 * ex[2 * k], eyl1 * ex[2 * k + 1]};
        }
    }

    // this lane's 32 samples: rows 2*sub, 2*sub+1 are contiguous in memory
    v2f smp2[16];
    {
        const float4* dp = reinterpret_cast<const float4*>(data + (size_t)job * 256 + sub * 32);
        #pragma unroll
        for (int q = 0; q < 8; ++q) {
            float4 v = dp[q];
            smp2[2 * q + 0] = (v2f){v.x, v.y};
            smp2[2 * q + 1] = (v2f){v.z, v.w};
        }
    }

    // S_psf over all 256 pixels (folded -1 terms of df)
    float spsf;
    {
        v2f sp = {0.0f, 0.0f};
        #pragma unroll
        for (int p = 0; p < 16; ++p) sp += g2[p];
        spsf = grpsum8(sp[0] + sp[1]);
    }

    for (int it = 0; it < ITERS; ++it) {
        const float bge = bg + 1e-9f;   // g>=0 guarantees mu>=1e-9 (matches ref clip regime)
        v2f A0 = {0.0f, 0.0f}, A1 = {0.0f, 0.0f}, A2 = {0.0f, 0.0f};
        #pragma unroll
        for (int p = 0; p < 16; ++p) {
            v2f mu = g2[p] * I + bge;                       // v_pk_fma_f32
            float pr = mu[0] * mu[1];
            float rp = __builtin_amdgcn_rcpf(pr);           // one trans op per 2 px
            v2f r  = (v2f){rp * mu[1], rp * mu[0]};         // {1/mu0, 1/mu1}
            v2f u  = smp2[p] * r * r;                       // smp/mu^2
            v2f w  = u * g2[p];
            A0 += u;
            A1 += w;
            A2 += w * g2[p];
        }
        float U0 = grpsum8(A0[0] + A0[1]);
        float U1 = grpsum8(A1[0] + A1[1]);
        float U2 = grpsum8(A2[0] + A2[1]);

        // identity t = u*mu: sum(smp/mu) = I*U1 + bg*U0, sum(smp/mu * g) = I*U2 + bg*U1
        float a00 = U2 + LAMBDA_;
        float a01 = U1;
        float a11 = U0 + LAMBDA_;
        float b0 = fmaf(I, U2, bg * U1) - spsf;
        float b1 = fmaf(I, U1, bg * U0) - 256.0f;
        float det = fmaf(a00, a11, -(a01 * a01));
        float rd = __builtin_amdgcn_rcpf(det);
        float dI  = fmaf(a11, b0, -(a01 * b1)) * rd;
        float dbg = fmaf(a00, b1, -(a01 * b0)) * rd;
        I  = fminf(fmaxf(I + dI, 1.0f), 1000000.0f);
        bg = fminf(fmaxf(bg + dbg, 1.0f), 1000.0f);
    }

    // epilogue: CRLB + chisq
    float F00 = 0.0f, F01 = 0.0f, F11 = 0.0f, chis = 0.0f;
    #pragma unroll
    for (int p = 0; p < 16; ++p) {
        #pragma unroll
        for (int h = 0; h < 2; ++h) {
            float g = g2[p][h];
            float mu = fmaf(I, g, bg);                   // ref uses unclipped mu for residual
            float inv = __builtin_amdgcn_rcpf(fmaxf(mu, 1e-9f));
            F00 = fmaf(g * g, inv, F00);
            F01 = fmaf(g, inv, F01);
            F11 += inv;
            float d = smp2[p][h] - mu;
            chis = fmaf(d * d, __builtin_amdgcn_rcpf(mu + 0.01f), chis);
        }
    }
    F00  = grpsum8(F00);
    F01  = grpsum8(F01);
    F11  = grpsum8(F11);
    chis = grpsum8(chis);

    if (sub == 0) {
        float detF = fmaf(F00, F11, -(F01 * F01));
        float rdF = __builtin_amdgcn_rcpf(detF);
        float* o = out + (size_t)job * 5;
        o[0] = I;
        o[1] = bg;
        o[2] = sqrtf(F11 * rdF);
        o[3] = sqrtf(F00 * rdF);
        o[4] = chis;
    }
}

extern "C" void kernel_launch(void* const* d_in, const int* in_sizes, int n_in,
                              void* d_out, int out_size, void* d_ws, size_t ws_size,
                              hipStream_t stream) {
    const float* params = (const float*)d_in[0];
    const float* data   = (const float*)d_in[1];
    float* out = (float*)d_out;
    int nspots = in_sizes[0] / 5;
    int njobs = nspots * PATTERNS;
    long long nthreads = (long long)njobs * 8;
    int blocks = (int)((nthreads + 255) / 256);
    intensity_kernel<<<dim3(blocks), dim3(256), 0, stream>>>(params, data, out, njobs);
}